// Round 1
// baseline (288.940 us; speedup 1.0000x reference)
//
#include <hip/hip_runtime.h>

// Gaussian blur (theta=3, truncate=4 -> r=12, 25 taps), separable, minus identity.
// src: (4, 512, 512, 21) fp32 NHWC.  out = V(H(src)) - src with zero padding.
// Pass 1: vertical conv -> fp16 intermediate in d_ws (44 MB).
// Pass 2: horizontal conv from fp16 + subtract src -> fp32 out.

#define BATCH 4
#define HH 512
#define WW 512
#define CC 21
#define WC (WW * CC)            // 10752 floats per row
#define IMG ((size_t)HH * WC)   // elems per batch image
#define RAD 12

// g(d) = exp(-d^2/18), index = d + 12 (symmetric)
__device__ static constexpr float GW[25] = {
    3.3546263e-04f, 1.2038700e-03f, 3.8659300e-03f, 1.1108997e-02f, 2.8565500e-02f,
    6.5728500e-02f, 1.3533528e-01f, 2.4935221e-01f, 4.1111229e-01f, 6.0653066e-01f,
    8.0073740e-01f, 9.4595947e-01f, 1.0000000e+00f, 9.4595947e-01f, 8.0073740e-01f,
    6.0653066e-01f, 4.1111229e-01f, 2.4935221e-01f, 1.3533528e-01f, 6.5728500e-02f,
    2.8565500e-02f, 1.1108997e-02f, 3.8659300e-03f, 1.2038700e-03f, 3.3546263e-04f
};

// ---------------- Pass 1: vertical ----------------
// Block: 256 threads, each owns 4 consecutive flat cols (float4) x BH1 output rows.
// Register accumulation: each loaded input row feeds up to 25 row-accumulators.
constexpr int BH1 = 32;

__global__ __launch_bounds__(256, 2)
void vconv_kernel(const float* __restrict__ src, _Float16* __restrict__ v)
{
    const int f  = blockIdx.x * 1024 + threadIdx.x * 4;   // flat col (w*c)
    const int i0 = blockIdx.y * BH1;                      // first output row
    const int b  = blockIdx.z;
    if (f >= WC) return;

    const float* s = src + (size_t)b * IMG + f;

    float acc[BH1][4];
#pragma unroll
    for (int p = 0; p < BH1; ++p) {
        acc[p][0] = 0.f; acc[p][1] = 0.f; acc[p][2] = 0.f; acc[p][3] = 0.f;
    }

#pragma unroll
    for (int a = 0; a < BH1 + 2 * RAD; ++a) {
        const int row = i0 - RAD + a;
        float4 x = make_float4(0.f, 0.f, 0.f, 0.f);
        if (row >= 0 && row < HH)
            x = *(const float4*)(s + (size_t)row * WC);
#pragma unroll
        for (int p = 0; p < BH1; ++p) {
            // dy = (row) - (i0+p) = a - 12 - p in [-12,12]  <=>  0 <= a-p <= 24
            if (a - p >= 0 && a - p <= 2 * RAD) {
                const float w = GW[a - p];   // compile-time index -> literal
                acc[p][0] = fmaf(w, x.x, acc[p][0]);
                acc[p][1] = fmaf(w, x.y, acc[p][1]);
                acc[p][2] = fmaf(w, x.z, acc[p][2]);
                acc[p][3] = fmaf(w, x.w, acc[p][3]);
            }
        }
    }

    _Float16* vp = v + (size_t)b * IMG + (size_t)i0 * WC + f;
#pragma unroll
    for (int p = 0; p < BH1; ++p) {
        union { _Float16 h[4]; uint2 q; } pk;
        pk.h[0] = (_Float16)acc[p][0];
        pk.h[1] = (_Float16)acc[p][1];
        pk.h[2] = (_Float16)acc[p][2];
        pk.h[3] = (_Float16)acc[p][3];
        *(uint2*)(vp + (size_t)p * WC) = pk.q;   // 8B aligned: f%4==0
    }
}

// ---------------- Pass 2: horizontal + subtract ----------------
// Thread owns channel cc and P2 consecutive pixels of one row.
// Horizontal taps are flat offsets of 21*dx; zero-pad in flat space == pixel space.
constexpr int P2 = 8;

__global__ __launch_bounds__(256, 8)
void hconv_kernel(const _Float16* __restrict__ v, const float* __restrict__ src,
                  float* __restrict__ out)
{
    const int tid = threadIdx.x;
    if (tid >= 252) return;                 // 12 pixel-groups x 21 channels
    const int bp = tid / 21;                // pixel group 0..11
    const int cc = tid - bp * 21;           // channel 0..20

    const int row = blockIdx.y;
    const int b   = blockIdx.z;
    const int j0  = blockIdx.x * 96 + bp * P2;   // first output pixel of this thread

    const _Float16* vrow = v + (size_t)b * IMG + (size_t)row * WC + cc;

    float acc[P2];
#pragma unroll
    for (int p = 0; p < P2; ++p) acc[p] = 0.f;

#pragma unroll
    for (int a = 0; a < P2 + 2 * RAD; ++a) {
        const int jt = j0 + a - RAD;        // tap pixel
        float x = 0.f;
        if (jt >= 0 && jt < WW)
            x = (float)vrow[(size_t)jt * CC];
#pragma unroll
        for (int p = 0; p < P2; ++p) {
            if (a - p >= 0 && a - p <= 2 * RAD)
                acc[p] = fmaf(GW[a - p], x, acc[p]);
        }
    }

    const size_t base = (size_t)b * IMG + (size_t)row * WC + cc;
#pragma unroll
    for (int p = 0; p < P2; ++p) {
        const int j = j0 + p;
        if (j < WW) {
            const size_t idx = base + (size_t)j * CC;
            out[idx] = acc[p] - src[idx];
        }
    }
}

extern "C" void kernel_launch(void* const* d_in, const int* in_sizes, int n_in,
                              void* d_out, int out_size, void* d_ws, size_t ws_size,
                              hipStream_t stream)
{
    const float* src = (const float*)d_in[0];
    float*       out = (float*)d_out;
    _Float16*    v   = (_Float16*)d_ws;     // 4*512*10752*2 = 44 MB

    // Pass 1: vertical. 11 col-tiles (ceil(10752/1024)), 16 row bands, 4 batches.
    dim3 g1(11, HH / BH1, BATCH);
    vconv_kernel<<<g1, 256, 0, stream>>>(src, v);

    // Pass 2: horizontal + subtract. 6 pixel tiles of 96, 512 rows, 4 batches.
    dim3 g2(6, HH, BATCH);
    hconv_kernel<<<g2, 256, 0, stream>>>(v, src, out);
}

// Round 2
// 193.659 us; speedup vs baseline: 1.4920x; 1.4920x over previous
//
#include <hip/hip_runtime.h>

// Gaussian blur (theta=3, truncate=4 -> r=12, 25 taps), separable, minus identity.
// src: (4, 512, 512, 21) fp32 NHWC.  out = V(H(src)) - src with zero padding.
// Pass 1: vertical conv -> fp16 intermediate (NHWC flat) in d_ws (44 MB).
// Pass 2: one block per row; LDS channel-planar transpose; 25-tap conv from LDS
//         with aligned b32 reads; LDS re-transpose; coalesced float4 out.

#define BATCH 4
#define HH 512
#define WW 512
#define CC 21
#define WC (WW * CC)            // 10752 floats per row
#define IMG ((size_t)HH * WC)   // elems per batch image
#define RAD 12

// g(d) = exp(-d^2/18), index = d + 12 (symmetric)
__device__ static constexpr float GW[25] = {
    3.3546263e-04f, 1.2038700e-03f, 3.8659300e-03f, 1.1108997e-02f, 2.8565500e-02f,
    6.5728500e-02f, 1.3533528e-01f, 2.4935221e-01f, 4.1111229e-01f, 6.0653066e-01f,
    8.0073740e-01f, 9.4595947e-01f, 1.0000000e+00f, 9.4595947e-01f, 8.0073740e-01f,
    6.0653066e-01f, 4.1111229e-01f, 2.4935221e-01f, 1.3533528e-01f, 6.5728500e-02f,
    2.8565500e-02f, 1.1108997e-02f, 3.8659300e-03f, 1.2038700e-03f, 3.3546263e-04f
};

// ---------------- Pass 1: vertical ----------------
// 256 threads; thread owns 4 consecutive flat cols (float4) x BH1 output rows.
// BH1=16: 64 accumulator VGPRs -> no spill, full unroll -> literal weights.
constexpr int BH1 = 16;

__global__ __launch_bounds__(256)
void vconv_kernel(const float* __restrict__ src, _Float16* __restrict__ v)
{
    const int f  = blockIdx.x * 1024 + threadIdx.x * 4;   // flat col (w*c)
    const int i0 = blockIdx.y * BH1;                      // first output row
    const int b  = blockIdx.z;
    if (f >= WC) return;

    const float* s = src + (size_t)b * IMG + f;

    float acc[BH1][4];
#pragma unroll
    for (int p = 0; p < BH1; ++p) {
        acc[p][0] = 0.f; acc[p][1] = 0.f; acc[p][2] = 0.f; acc[p][3] = 0.f;
    }

#pragma unroll
    for (int a = 0; a < BH1 + 2 * RAD; ++a) {
        const int row = i0 - RAD + a;
        float4 x = make_float4(0.f, 0.f, 0.f, 0.f);
        if (row >= 0 && row < HH)
            x = *(const float4*)(s + (size_t)row * WC);
#pragma unroll
        for (int p = 0; p < BH1; ++p) {
            if (a - p >= 0 && a - p <= 2 * RAD) {
                const float w = GW[a - p];   // compile-time index -> literal
                acc[p][0] = fmaf(w, x.x, acc[p][0]);
                acc[p][1] = fmaf(w, x.y, acc[p][1]);
                acc[p][2] = fmaf(w, x.z, acc[p][2]);
                acc[p][3] = fmaf(w, x.w, acc[p][3]);
            }
        }
    }

    _Float16* vp = v + (size_t)b * IMG + (size_t)i0 * WC + f;
#pragma unroll
    for (int p = 0; p < BH1; ++p) {
        union { _Float16 h[4]; uint2 q; } pk;
        pk.h[0] = (_Float16)acc[p][0];
        pk.h[1] = (_Float16)acc[p][1];
        pk.h[2] = (_Float16)acc[p][2];
        pk.h[3] = (_Float16)acc[p][3];
        *(uint2*)(vp + (size_t)p * WC) = pk.q;   // 8B aligned: f%4==0
    }
}

// ---------------- Pass 2: horizontal + subtract ----------------
// One block (384 threads) per (batch, row).
// LDS phase A: v row staged channel-planar: v_d[c][jd], jd = dword (2 fp16),
//   row stride 273 dwords (odd -> conflict-free), fp16 index = 16 + j
//   (16 zero-pad halves each side absorb the j<0 / j>=512 taps).
// Compute: thread (c, j0=32*jg) reads 28 aligned dwords, 800 literal-weight FMAs.
// LDS phase B: results re-staged NHWC fp32 (aliased buffer), then coalesced
//   float4 read + src subtract + store.
constexpr int SD  = 273;   // dword stride per channel row in LDS
constexpr int NT2 = 384;

__global__ __launch_bounds__(NT2)
void hconv_kernel(const _Float16* __restrict__ v, const float* __restrict__ src,
                  float* __restrict__ out)
{
    __shared__ float out_l[WC];                 // 43008 B
    unsigned int* v_d = (unsigned int*)out_l;   // alias; uses 21*273*4 = 22932 B

    const int tid = threadIdx.x;
    const int row = blockIdx.x;
    const int b   = blockIdx.y;
    const size_t rowbase = ((size_t)b * HH + row) * WC;

    // ---- phase A: zero pads + stage v row transposed ----
    if (tid < 21 * 17) {                        // 17 pad dwords per channel
        const int c = tid / 17, m = tid % 17;
        const int jd = (m < 8) ? m : (256 + m); // dwords [0..7] and [264..272]
        v_d[c * SD + jd] = 0u;
    }
    {
        const unsigned int* vrow32 = (const unsigned int*)(v + rowbase);
        _Float16* vh = (_Float16*)v_d;
#pragma unroll
        for (int k = 0; k < 14; ++k) {
            const int g = tid + k * NT2;        // 384*14 = 5376 dwords exactly
            union { unsigned int u; _Float16 h[2]; } cv;
            cv.u = vrow32[g];
            const int f0 = 2 * g;
            const int c0 = f0 % CC, j0 = f0 / CC;
            const int f1 = f0 + 1;
            const int c1 = f1 % CC, j1 = f1 / CC;
            vh[c0 * (2 * SD) + 16 + j0] = cv.h[0];
            vh[c1 * (2 * SD) + 16 + j1] = cv.h[1];
        }
    }
    __syncthreads();

    // ---- compute: 336 active threads, each (c, j0..j0+31) ----
    float res[32];
    const bool active = tid < 21 * 16;
    int c = 0, j0 = 0;
    if (active) {
        c  = tid % CC;
        j0 = (tid / CC) * 32;
        const int base = c * SD + (j0 + 4) / 2;  // dword of fp16 idx (16+j0-12)
        float w[56];
#pragma unroll
        for (int m = 0; m < 28; ++m) {
            union { unsigned int u; _Float16 h[2]; } cv;
            cv.u = v_d[base + m];
            w[2 * m]     = (float)cv.h[0];
            w[2 * m + 1] = (float)cv.h[1];
        }
#pragma unroll
        for (int k = 0; k < 32; ++k) {
            float a = 0.f;
#pragma unroll
            for (int t = 0; t < 25; ++t)
                a = fmaf(GW[t], w[k + t], a);
            res[k] = a;
        }
    }
    __syncthreads();

    // ---- phase B: re-stage NHWC fp32 (overwrites v_d region) ----
    if (active) {
#pragma unroll
        for (int k = 0; k < 32; ++k)
            out_l[(j0 + k) * CC + c] = res[k];
    }
    __syncthreads();

    // ---- final: coalesced subtract + store ----
    const float4* srcv = (const float4*)(src + rowbase);
    float4*       outv = (float4*)(out + rowbase);
    const float4* olv  = (const float4*)out_l;
#pragma unroll
    for (int k = 0; k < 7; ++k) {               // 384*7 = 2688 float4 exactly
        const int g = tid + k * NT2;
        const float4 o = olv[g];
        const float4 s = srcv[g];
        outv[g] = make_float4(o.x - s.x, o.y - s.y, o.z - s.z, o.w - s.w);
    }
}

extern "C" void kernel_launch(void* const* d_in, const int* in_sizes, int n_in,
                              void* d_out, int out_size, void* d_ws, size_t ws_size,
                              hipStream_t stream)
{
    const float* src = (const float*)d_in[0];
    float*       out = (float*)d_out;
    _Float16*    v   = (_Float16*)d_ws;     // 4*512*10752*2 = 44 MB

    dim3 g1(11, HH / BH1, BATCH);           // 11 col-tiles, 32 row bands, 4 batches
    vconv_kernel<<<g1, 256, 0, stream>>>(src, v);

    dim3 g2(HH, BATCH);                     // one block per (row, batch)
    hconv_kernel<<<g2, NT2, 0, stream>>>(v, src, out);
}